// Round 1
// baseline (139.804 us; speedup 1.0000x reference)
//
#include <hip/hip_runtime.h>
#include <hip/hip_bf16.h>

// Problem constants: B=16, D=256, T_enc=512, T_dec=2048
#define NB 16
#define ND 256
#define NK 512    // T_enc (contraction dim)
#define NT 2048   // T_dec (output cols)

// Tile config: BM=128, BN=128, BK=32, 256 threads (4 waves, 2x2 wave grid,
// each wave computes 64x64 via 4x4 grid of 16x16x32 bf16 MFMAs).
// Pipelined: double-buffered LDS, 1-deep register prefetch (T14 split),
// single barrier per K-step.
#define BM 128
#define BN 128
#define BK 32
#define NSTEP (NK / BK)   // 16
#define RSA 40   // A LDS row stride in bf16 (80B: 16B-aligned for b128, 2-way banks)
#define RSB 36   // B^T LDS row stride in bf16 (72B = 18 dwords: <=2-way banks on b64)

typedef __attribute__((ext_vector_type(8))) short short8;   // 8 bf16 = 4 VGPRs
typedef __attribute__((ext_vector_type(4))) float f32x4;    // MFMA accumulator

union S8U { short8 v; uint2 u[2]; };
union BF2U { __hip_bfloat162 h; unsigned int u; };

__device__ inline unsigned int pack2bf(float a, float b) {
    BF2U c; c.h = __float22bfloat162_rn(make_float2(a, b));
    return c.u;
}

__global__ __launch_bounds__(256, 2)
void bmm_bf16_mfma(const float* __restrict__ x, const float* __restrict__ path,
                   float* __restrict__ out) {
    const int n0 = blockIdx.x * BN;
    const int m0 = blockIdx.y * BM;
    const int b  = blockIdx.z;
    const int t    = threadIdx.x;
    const int lane = t & 63;
    const int wv   = t >> 6;          // wave id 0..3
    const int wr   = (wv >> 1) * 64;  // wave row offset in tile
    const int wc   = (wv & 1) * 64;   // wave col offset in tile
    const int q    = lane >> 4;       // quad 0..3
    const int lm   = lane & 15;

    __shared__ unsigned short As[2][BM * RSA]; // [m][k], k-contiguous, double-buffered
    __shared__ unsigned short Bs[2][BN * RSB]; // [n][k] (transposed), k-contiguous

    const float* xg = x    + ((size_t)b * ND + m0) * NK;   // A tile base
    const float* pg = path + (size_t)b * NK * NT + n0;     // B tile base

    // staging geometry (constant per thread)
    const int rowA = t >> 3;   // + i*32 per chunk
    const int c4   = t & 7;

    f32x4 acc[4][4];
#pragma unroll
    for (int i = 0; i < 4; ++i)
#pragma unroll
        for (int j = 0; j < 4; ++j)
            acc[i][j] = (f32x4){0.f, 0.f, 0.f, 0.f};

    // Prefetch registers (1 K-step in flight): A as float4, B as 4x4 scalars
    float4 pa[4];
    float  pb[4][4];

    auto load_tile = [&](int k0) {
        // A: 128x32 fp32, float4 per thread x4 (1 KiB per wave instr)
#pragma unroll
        for (int i = 0; i < 4; ++i)
            pa[i] = *reinterpret_cast<const float4*>(
                xg + (size_t)(rowA + i * 32) * NK + k0 + c4 * 4);
        // B (transposed consumption): lane-stride-1 scalar loads, lane owns one n,
        // 4 k-rows per group (256B per wave instr, coalesced)
#pragma unroll
        for (int i = 0; i < 4; ++i) {
            const int p   = wv * 4 + i;      // 0..15
            const int kr4 = p >> 1;          // group of 4 k-rows
            const int n   = (p & 1) * 64 + lane;
            const float* src = pg + (size_t)(k0 + kr4 * 4) * NT + n;
            pb[i][0] = src[0 * NT];
            pb[i][1] = src[1 * NT];
            pb[i][2] = src[2 * NT];
            pb[i][3] = src[3 * NT];
        }
    };

    auto write_tile = [&](int bsel) {
#pragma unroll
        for (int i = 0; i < 4; ++i) {
            uint2 w;
            w.x = pack2bf(pa[i].x, pa[i].y);
            w.y = pack2bf(pa[i].z, pa[i].w);
            *reinterpret_cast<uint2*>(&As[bsel][(rowA + i * 32) * RSA + c4 * 4]) = w;
        }
#pragma unroll
        for (int i = 0; i < 4; ++i) {
            const int p   = wv * 4 + i;
            const int kr4 = p >> 1;
            const int n   = (p & 1) * 64 + lane;
            uint2 w;
            w.x = pack2bf(pb[i][0], pb[i][1]);
            w.y = pack2bf(pb[i][2], pb[i][3]);
            *reinterpret_cast<uint2*>(&Bs[bsel][n * RSB + kr4 * 4]) = w;
        }
    };

    auto compute = [&](int bsel) {
        short8 af[4];
        short8 bfrg[4];
#pragma unroll
        for (int mt = 0; mt < 4; ++mt)
            af[mt] = *reinterpret_cast<const short8*>(
                &As[bsel][(wr + mt * 16 + lm) * RSA + q * 8]); // 16B aligned
#pragma unroll
        for (int nt = 0; nt < 4; ++nt) {
            S8U s;
            s.u[0] = *reinterpret_cast<const uint2*>(
                &Bs[bsel][(wc + nt * 16 + lm) * RSB + q * 8]);
            s.u[1] = *reinterpret_cast<const uint2*>(
                &Bs[bsel][(wc + nt * 16 + lm) * RSB + q * 8 + 4]);
            bfrg[nt] = s.v;
        }
        // Swapped operands: D' = (A*B)^T per 16x16 tile. Lane then holds
        // C[m = lm][n = q*4 + r] -> contiguous along n -> float4 epilogue stores.
#pragma unroll
        for (int mt = 0; mt < 4; ++mt)
#pragma unroll
            for (int nt = 0; nt < 4; ++nt)
                acc[mt][nt] = __builtin_amdgcn_mfma_f32_16x16x32_bf16(
                    bfrg[nt], af[mt], acc[mt][nt], 0, 0, 0);
    };

    // ---- Pipeline: prologue stages step 0; each iter prefetches s+1,
    // computes s, writes s+1 into the other buffer, one barrier.
    load_tile(0);
    write_tile(0);
    __syncthreads();

    int cur = 0;
    for (int s = 0; s < NSTEP - 1; ++s) {
        load_tile((s + 1) * BK);   // issue global loads early (in flight over MFMA)
        compute(cur);              // ds_read + 16 MFMA on current buffer
        write_tile(cur ^ 1);       // vmcnt wait happens here, after MFMA issued
        __syncthreads();           // single barrier per K-step
        cur ^= 1;
    }
    compute(cur);                  // last step, no prefetch/barrier needed

    // ---- Epilogue: swapped layout -> lane (q,lm) holds rows m=lm, cols q*4+0..3
    float* og = out + ((size_t)b * ND + m0 + wr) * NT + n0 + wc;
#pragma unroll
    for (int mt = 0; mt < 4; ++mt)
#pragma unroll
        for (int nt = 0; nt < 4; ++nt)
            *reinterpret_cast<f32x4*>(
                &og[(size_t)(mt * 16 + lm) * NT + nt * 16 + q * 4]) = acc[mt][nt];
}

extern "C" void kernel_launch(void* const* d_in, const int* in_sizes, int n_in,
                              void* d_out, int out_size, void* d_ws, size_t ws_size,
                              hipStream_t stream) {
    const float* x    = (const float*)d_in[0];   // [16, 256, 512]
    const float* path = (const float*)d_in[1];   // [16, 512, 2048]
    float* out        = (float*)d_out;           // [16, 256, 2048]
    dim3 grid(NT / BN, ND / BM, NB);             // (16, 2, 16) = 512 blocks
    dim3 block(256);
    bmm_bf16_mfma<<<grid, block, 0, stream>>>(x, path, out);
}

// Round 2
// 131.663 us; speedup vs baseline: 1.0618x; 1.0618x over previous
//
#include <hip/hip_runtime.h>
#include <hip/hip_bf16.h>

// Problem constants: B=16, D=256, T_enc=512, T_dec=2048
#define NB 16
#define ND 256
#define NK 512    // T_enc (contraction dim)
#define NT 2048   // T_dec (output cols)

// Tile config: BM=64, BN=128, BK=32, 256 threads (4 waves, 2x2 wave grid,
// each wave computes 32x64 via 2x4 grid of 16x16x32 bf16 MFMAs).
// Round-0 two-barrier structure (load+cvt+LDS-write, sync, compute, sync) —
// NO register prefetch (round-1 regression: latency-bound, prefetch neutral-to-bad).
// Smaller BM -> 1024 blocks = 4 blocks/CU (TLP doubles vs 2/CU).
#define BM 64
#define BN 128
#define BK 32
#define RSA 40   // A LDS row stride in bf16 (80B: 16B-aligned for b128, <=2-way banks)
#define RSB 36   // B^T LDS row stride in bf16 (72B = 18 dwords: <=2-way banks on b64)

typedef __attribute__((ext_vector_type(8))) short short8;   // 8 bf16 = 4 VGPRs
typedef __attribute__((ext_vector_type(4))) float f32x4;    // MFMA accumulator

union S8U { short8 v; uint2 u[2]; };
union BF2U { __hip_bfloat162 h; unsigned int u; };

__device__ inline unsigned int pack2bf(float a, float b) {
    BF2U c; c.h = __float22bfloat162_rn(make_float2(a, b));
    return c.u;
}

__global__ __launch_bounds__(256, 4)
void bmm_bf16_mfma(const float* __restrict__ x, const float* __restrict__ path,
                   float* __restrict__ out) {
    // ---- Chunked XCD swizzle (T1, bijective: 1024 % 8 == 0).
    // XCD k gets a contiguous run of 128 tile-ids; tile-id = mblk + 4*nblk + 64*b
    // (m fastest) so the 4 m-blocks sharing a path panel land on one XCD's L2.
    const int id  = blockIdx.x;                 // 0..1023
    const int swz = (id & 7) * 128 + (id >> 3);
    const int b    = swz >> 6;                  // batch 0..15
    const int rem  = swz & 63;
    const int n0   = (rem >> 2) * BN;           // 16 n-blocks
    const int m0   = (rem & 3)  * BM;           // 4 m-blocks

    const int t    = threadIdx.x;
    const int lane = t & 63;
    const int wv   = t >> 6;          // wave id 0..3
    const int wr   = (wv >> 1) * 32;  // wave row offset in tile (2 waves over 64 rows)
    const int wc   = (wv & 1) * 64;   // wave col offset in tile (2 waves over 128 cols)
    const int q    = lane >> 4;       // quad 0..3
    const int lm   = lane & 15;

    __shared__ unsigned short As[BM * RSA]; // [m][k], k-contiguous
    __shared__ unsigned short Bs[BN * RSB]; // [n][k] (transposed), k-contiguous

    const float* xg = x    + ((size_t)b * ND + m0) * NK;   // A tile base
    const float* pg = path + (size_t)b * NK * NT + n0;     // B tile base

    f32x4 acc[2][4];
#pragma unroll
    for (int i = 0; i < 2; ++i)
#pragma unroll
        for (int j = 0; j < 4; ++j)
            acc[i][j] = (f32x4){0.f, 0.f, 0.f, 0.f};

    for (int k0 = 0; k0 < NK; k0 += BK) {
        // ---- Stage A: 64x32 fp32 -> bf16 LDS. float4 loads, b64 LDS writes.
#pragma unroll
        for (int i = 0; i < 2; ++i) {
            int f   = t + i * 256;       // 0..511 float4s
            int row = f >> 3;            // 8 float4 per 32-wide row
            int c4  = f & 7;
            float4 v = *reinterpret_cast<const float4*>(xg + (size_t)row * NK + k0 + c4 * 4);
            uint2 p;
            p.x = pack2bf(v.x, v.y);
            p.y = pack2bf(v.z, v.w);
            *reinterpret_cast<uint2*>(&As[row * RSA + c4 * 4]) = p;
        }
        // ---- Stage B (transposed): lane-stride-1 scalar loads so lane owns one n;
        // pack 4 k-values -> one b64 write into Bs[n][k]. Conflict-free (<=2-way).
#pragma unroll
        for (int i = 0; i < 4; ++i) {
            int p   = wv * 4 + i;        // 0..15
            int kr4 = p >> 1;            // 0..7 : group of 4 k-rows
            int ng  = p & 1;             // 0..1 : n half
            int n   = ng * 64 + lane;
            const float* src = pg + (size_t)(k0 + kr4 * 4) * NT + n;
            float f0 = src[0 * NT];
            float f1 = src[1 * NT];
            float f2 = src[2 * NT];
            float f3 = src[3 * NT];
            uint2 pk;
            pk.x = pack2bf(f0, f1);
            pk.y = pack2bf(f2, f3);
            *reinterpret_cast<uint2*>(&Bs[n * RSB + kr4 * 4]) = pk;
        }
        __syncthreads();

        // ---- Fragments + MFMA
        short8 af[2];
        short8 bfr[4];
#pragma unroll
        for (int mt = 0; mt < 2; ++mt) {
            int row = wr + mt * 16 + lm;
            af[mt] = *reinterpret_cast<const short8*>(&As[row * RSA + q * 8]); // 16B aligned
        }
#pragma unroll
        for (int nt = 0; nt < 4; ++nt) {
            int n = wc + nt * 16 + lm;
            S8U s;
            s.u[0] = *reinterpret_cast<const uint2*>(&Bs[n * RSB + q * 8]);
            s.u[1] = *reinterpret_cast<const uint2*>(&Bs[n * RSB + q * 8 + 4]);
            bfr[nt] = s.v;
        }
        // Swapped operands: per-16x16 tile D' = (A*B)^T. Lane (q,lm) then holds
        // C[m = lm][n = q*4 + r] -> contiguous along n -> float4 epilogue stores.
        // (Harness-verified correct in round 1.)
#pragma unroll
        for (int mt = 0; mt < 2; ++mt)
#pragma unroll
            for (int nt = 0; nt < 4; ++nt)
                acc[mt][nt] = __builtin_amdgcn_mfma_f32_16x16x32_bf16(
                    bfr[nt], af[mt], acc[mt][nt], 0, 0, 0);

        __syncthreads();
    }

    // ---- Epilogue: swapped layout -> lane (q,lm) holds rows m=lm, cols q*4+0..3
    float* og = out + ((size_t)b * ND + m0 + wr) * NT + n0 + wc;
#pragma unroll
    for (int mt = 0; mt < 2; ++mt)
#pragma unroll
        for (int nt = 0; nt < 4; ++nt)
            *reinterpret_cast<f32x4*>(
                &og[(size_t)(mt * 16 + lm) * NT + nt * 16 + q * 4]) = acc[mt][nt];
}

extern "C" void kernel_launch(void* const* d_in, const int* in_sizes, int n_in,
                              void* d_out, int out_size, void* d_ws, size_t ws_size,
                              hipStream_t stream) {
    const float* x    = (const float*)d_in[0];   // [16, 256, 512]
    const float* path = (const float*)d_in[1];   // [16, 512, 2048]
    float* out        = (float*)d_out;           // [16, 256, 2048]
    dim3 grid(1024);                             // 16 n * 4 m * 16 b, 1D for swizzle
    dim3 block(256);
    bmm_bf16_mfma<<<grid, block, 0, stream>>>(x, path, out);
}